// Round 1
// baseline (246.157 us; speedup 1.0000x reference)
//
#include <hip/hip_runtime.h>

namespace {

constexpr int L = 3264;
constexpr int K = 12;
constexpr int S = 8;
constexpr int B = 64;
constexpr int A = 4;
constexpr int R = 816;            // L / LOCC
constexpr int NOFF = 21;          // delays -10..10
constexpr int PEAK_STEP = L / K;  // 272
constexpr float TWO_PI = 6.28318530717958647692f;
constexpr int NCHUNK = (L + 255) / 256;  // 13

// ---------------------------------------------------------------------------
// Kernel 1: per (s,b): timing-offset search via direct DFT at 21 candidate
// bins, then OCC-demux average h_avg[s,b,a,816] using the LDS twiddle table.
// ---------------------------------------------------------------------------
__global__ __launch_bounds__(256)
void k_stage1(const float* __restrict__ lsr, const float* __restrict__ lsi,
              const int* __restrict__ cs,
              int* __restrict__ toff_out, int* __restrict__ m_out,
              float2* __restrict__ havg)
{
    __shared__ float2 tw[L];        // exp(+2*pi*i*j/L), 26112 B
    __shared__ float2 lsc[A][L];    // staged ls rows, 104448 B
    __shared__ float taskpow[NOFF * A];
    __shared__ int m_sh;

    const int sb = blockIdx.x;
    const int s = sb / B;
    const int tid = threadIdx.x;
    const int lane = tid & 63, wid = tid >> 6;

    // twiddle table
    for (int j = tid; j < L; j += 256) {
        float sv, cv;
        __sincosf((TWO_PI / (float)L) * (float)j, &sv, &cv);
        tw[j] = make_float2(cv, sv);
    }
    // stage ls (4 antenna rows)
    const size_t base = (size_t)sb * A * L;
    for (int a = 0; a < A; ++a) {
        const float* pr = lsr + base + (size_t)a * L;
        const float* pi = lsi + base + (size_t)a * L;
        for (int k2 = tid; k2 < L; k2 += 256)
            lsc[a][k2] = make_float2(pr[k2], pi[k2]);
    }
    __syncthreads();

    const int csv = cs[s];
    const int ideal = ((K - csv) % K) * PEAK_STEP;  // csv in [0,K) -> nonneg

    // 84 tasks = 21 offsets x 4 antennas; wave wid owns antenna wid
    for (int t = wid; t < NOFF * A; t += 4) {
        const int d = t >> 2;
        const int a = t & 3;
        int idx = (ideal + d - 10) % L; if (idx < 0) idx += L;
        float sre = 0.f, sim = 0.f;
        int j = (lane * idx) % L;
        const int step = (64 * idx) % L;
        #pragma unroll 4
        for (int k2 = lane; k2 < L; k2 += 64) {   // 51 iterations/lane
            const float2 x = lsc[a][k2];
            const float2 w = tw[j];
            sre += x.x * w.x - x.y * w.y;
            sim += x.x * w.y + x.y * w.x;
            j += step; if (j >= L) j -= L;
        }
        #pragma unroll
        for (int o = 32; o > 0; o >>= 1) {
            sre += __shfl_xor(sre, o);
            sim += __shfl_xor(sim, o);
        }
        if (lane == 0) taskpow[t] = sre * sre + sim * sim;
    }
    __syncthreads();

    if (tid == 0) {
        float best = -1.f; int bd = 0;
        for (int d = 0; d < NOFF; ++d) {
            const float p = taskpow[4*d+0] + taskpow[4*d+1] +
                            taskpow[4*d+2] + taskpow[4*d+3];
            if (p > best) { best = p; bd = d; }   // strict > => first max
        }
        const int toff = bd - 10;
        toff_out[sb] = toff;
        m_out[sb] = toff + ideal;
        m_sh = toff + ideal;
    }
    __syncthreads();

    int mp = m_sh % L; if (mp < 0) mp += L;

    // h_avg: mean over groups of 4 of ls * ph_m  (ph_m[l] == tw[(m*l)%L])
    for (int a = 0; a < A; ++a) {
        float2* dst = havg + ((size_t)sb * A + a) * R;
        for (int i = tid; i < R; i += 256) {
            const int l0 = i * 4;
            int j = (mp * l0) % L;          // <= 3263*3260 fits int32
            float are = 0.f, aim = 0.f;
            #pragma unroll
            for (int jj = 0; jj < 4; ++jj) {
                const float2 x = lsc[a][l0 + jj];
                const float2 w = tw[j];
                are += x.x * w.x - x.y * w.y;
                aim += x.x * w.y + x.y * w.x;
                j += mp; if (j >= L) j -= L;
            }
            dst[i] = make_float2(are * 0.25f, aim * 0.25f);
        }
    }
}

// ---------------------------------------------------------------------------
// Kernel 2: per (b,a,l): interp h_avg -> h_interp (regs for all 8 streams),
// recon/residual over s, apply residual + timing recovery, write out.
// ---------------------------------------------------------------------------
__global__ __launch_bounds__(256)
void k_final(const float* __restrict__ lsr, const float* __restrict__ lsi,
             const int* __restrict__ toff_arr, const int* __restrict__ m_arr,
             const float2* __restrict__ havg,
             float* __restrict__ out)
{
    const int bid = blockIdx.x;
    const int chunk = bid % NCHUNK;
    const int ba = bid / NCHUNK;
    const int b = ba >> 2;   // / A
    const int a = ba & 3;    // % A
    const int l = chunk * 256 + (int)threadIdx.x;
    if (l >= L) return;

    // interp coords: t = clip((l - 1.5)/4, 0, R-1)
    float t = ((float)l - 1.5f) * 0.25f;
    t = fminf(fmaxf(t, 0.0f), (float)(R - 1));
    const int i0 = (int)t;                 // floor, t >= 0
    const int i1 = min(i0 + 1, R - 1);
    const float frac = t - (float)i0;

    float hire[S], hiim[S], pmre[S], pmim[S];
    float rre = 0.f, rim = 0.f;

    #pragma unroll
    for (int s = 0; s < S; ++s) {
        const int sb = s * B + b;
        int mp = m_arr[sb] % L; if (mp < 0) mp += L;
        const int j = (mp * l) % L;
        float sv, cv;
        __sincosf((TWO_PI / (float)L) * (float)j, &sv, &cv);
        const float2 h0 = havg[((size_t)sb * A + a) * R + i0];
        const float2 h1 = havg[((size_t)sb * A + a) * R + i1];
        const float hr = h0.x * (1.f - frac) + h1.x * frac;
        const float hi = h0.y * (1.f - frac) + h1.y * frac;
        hire[s] = hr; hiim[s] = hi; pmre[s] = cv; pmim[s] = sv;
        // recon += h_int * conj(ph_m)
        rre += hr * cv + hi * sv;
        rim += hi * cv - hr * sv;
    }

    const size_t off0 = ((size_t)(b * A + a)) * L + l;  // stream 0 LS
    const float resre = lsr[off0] - rre;
    const float resim = lsi[off0] - rim;

    #pragma unroll
    for (int s = 0; s < S; ++s) {
        // h_wr = h_interp + residual * ph_m
        const float wre = hire[s] + resre * pmre[s] - resim * pmim[s];
        const float wim = hiim[s] + resre * pmim[s] + resim * pmre[s];
        // final = h_wr * conj(ph_T)
        int jt = (toff_arr[s * B + b] * l) % L; if (jt < 0) jt += L;
        float sv, cv;
        __sincosf((TWO_PI / (float)L) * (float)jt, &sv, &cv);
        const float fre = wre * cv + wim * sv;
        const float fim = wim * cv - wre * sv;
        const size_t o = (((size_t)(s * B + b)) * A + a) * L + l;
        out[o] = fre;
        out[(size_t)S * B * A * L + o] = fim;
    }
}

}  // namespace

extern "C" void kernel_launch(void* const* d_in, const int* in_sizes, int n_in,
                              void* d_out, int out_size, void* d_ws, size_t ws_size,
                              hipStream_t stream) {
    (void)in_sizes; (void)n_in; (void)out_size; (void)ws_size;
    const float* lsr = (const float*)d_in[0];
    const float* lsi = (const float*)d_in[1];
    const int*   cs  = (const int*)d_in[2];
    // d_in[3] (noise_powers) is unused: mmse_module is identity.

    int* toff = (int*)d_ws;                              // 512 ints
    int* marr = toff + 512;                              // 512 ints
    float2* havg = (float2*)((char*)d_ws + 4096);        // S*B*A*R float2 = 13.4 MB

    k_stage1<<<S * B, 256, 0, stream>>>(lsr, lsi, cs, toff, marr, havg);
    k_final<<<B * A * NCHUNK, 256, 0, stream>>>(lsr, lsi, toff, marr, havg,
                                                (float*)d_out);
}

// Round 3
// 173.892 us; speedup vs baseline: 1.4156x; 1.4156x over previous
//
#include <hip/hip_runtime.h>

namespace {

constexpr int L = 3264;
constexpr int K = 12;
constexpr int S = 8;
constexpr int B = 64;
constexpr int A = 4;
constexpr int R = 816;            // L / LOCC
constexpr int NOFF = 21;          // delays -10..10
constexpr int PEAK_STEP = L / K;  // 272
constexpr float TWO_PI = 6.28318530717958647692f;
constexpr int NCHUNK = (L + 255) / 256;  // 13

// ---------------------------------------------------------------------------
// Kernel 1: per (s,b). 8 waves: wave w handles antenna w>>1, half w&1.
// DFT at 21 consecutive candidate bins entirely in registers via the
// rotation recurrence  w_{d+1} = w_d * exp(i*2*pi*k/L).  Then ballot-argmax
// and OCC-demux average (h_avg) re-reading the L2-hot rows.
// ---------------------------------------------------------------------------
__global__ __launch_bounds__(512)
void k_stage1(const float* __restrict__ lsr, const float* __restrict__ lsi,
              const int* __restrict__ cs,
              int* __restrict__ toff_out, int* __restrict__ m_out,
              float2* __restrict__ havg)
{
    __shared__ float2 red[8][NOFF];
    __shared__ int m_sh;

    const int sb = blockIdx.x;
    const int s = sb >> 6;                   // sb / B
    const int tid = threadIdx.x;
    const int lane = tid & 63;
    const int w = tid >> 6;                  // wave 0..7
    const int a = w >> 1;                    // antenna
    const int h = w & 1;                     // half of the row

    const int csv = cs[s];
    const int ideal = ((K - csv) % K) * PEAK_STEP;     // nonneg
    int idx0 = (ideal - 10) % L; if (idx0 < 0) idx0 += L;

    const size_t rowbase = ((size_t)sb * A + a) * L;
    const float* __restrict__ pr = lsr + rowbase;
    const float* __restrict__ pi = lsi + rowbase;

    float ar[NOFF], ai[NOFF];
    #pragma unroll
    for (int d = 0; d < NOFF; ++d) { ar[d] = 0.f; ai[d] = 0.f; }

    for (int k = h * 64 + lane; k < L; k += 128) {
        const float xr = pr[k];
        const float xi = pi[k];
        const int j0 = (k * idx0) % L;                 // <= 10.7M, int32 ok
        float wr, wi, str, sti;
        __sincosf((TWO_PI / (float)L) * (float)j0, &wi, &wr);  // w = e^{i*2pi*j0/L}
        __sincosf((TWO_PI / (float)L) * (float)k,  &sti, &str); // step = e^{i*2pi*k/L}
        #pragma unroll
        for (int d = 0; d < NOFF; ++d) {
            ar[d] += xr * wr - xi * wi;
            ai[d] += xr * wi + xi * wr;
            const float nwr = wr * str - wi * sti;
            wi = wr * sti + wi * str;
            wr = nwr;
        }
    }

    // reduce each bin across the 64 lanes of this wave
    #pragma unroll
    for (int d = 0; d < NOFF; ++d) {
        float r = ar[d], im = ai[d];
        #pragma unroll
        for (int o = 32; o > 0; o >>= 1) {
            r  += __shfl_xor(r, o);
            im += __shfl_xor(im, o);
        }
        if (lane == 0) red[w][d] = make_float2(r, im);
    }
    __syncthreads();

    if (w == 0) {
        float pw = -1.f;
        if (lane < NOFF) {
            pw = 0.f;
            #pragma unroll
            for (int a2 = 0; a2 < A; ++a2) {
                const float2 u = red[2 * a2][lane];
                const float2 v = red[2 * a2 + 1][lane];
                const float rr = u.x + v.x;
                const float ii = u.y + v.y;
                pw += rr * rr + ii * ii;
            }
        }
        float mx = pw;
        #pragma unroll
        for (int o = 32; o > 0; o >>= 1) mx = fmaxf(mx, __shfl_xor(mx, o));
        const unsigned long long msk = __ballot(pw == mx);
        const int argd = __ffsll(msk) - 1;            // first max => jnp.argmax
        if (lane == 0) {
            const int toff = argd - 10;
            toff_out[sb] = toff;
            m_out[sb]    = toff + ideal;
            m_sh         = toff + ideal;
        }
    }
    __syncthreads();

    int mp = m_sh % L; if (mp < 0) mp += L;
    float smr, smi;
    __sincosf((TWO_PI / (float)L) * (float)mp, &smi, &smr);  // e^{i*2pi*mp/L}

    // h_avg: mean over groups of 4 of ls * ph_m, rows are L2-hot
    for (int aa = 0; aa < A; ++aa) {
        const float* __restrict__ qr = lsr + ((size_t)sb * A + aa) * L;
        const float* __restrict__ qi = lsi + ((size_t)sb * A + aa) * L;
        float2* __restrict__ dst = havg + ((size_t)sb * A + aa) * R;
        for (int i = tid; i < R; i += 512) {
            const int l0 = 4 * i;
            int j = (mp * l0) % L;                    // <= 10.7M, int32 ok
            float wr2, wi2;
            __sincosf((TWO_PI / (float)L) * (float)j, &wi2, &wr2);
            float are = 0.f, aim = 0.f;
            #pragma unroll
            for (int jj = 0; jj < 4; ++jj) {
                const float xr = qr[l0 + jj];
                const float xi = qi[l0 + jj];
                are += xr * wr2 - xi * wi2;
                aim += xr * wi2 + xi * wr2;
                const float nw = wr2 * smr - wi2 * smi;
                wi2 = wr2 * smi + wi2 * smr;
                wr2 = nw;
            }
            dst[i] = make_float2(are * 0.25f, aim * 0.25f);
        }
    }
}

// ---------------------------------------------------------------------------
// Kernel 2: per (b,a,l): interp h_avg -> h_interp (regs for all 8 streams),
// recon/residual over s, apply residual + timing recovery, write out.
// ---------------------------------------------------------------------------
__global__ __launch_bounds__(256)
void k_final(const float* __restrict__ lsr, const float* __restrict__ lsi,
             const int* __restrict__ toff_arr, const int* __restrict__ m_arr,
             const float2* __restrict__ havg,
             float* __restrict__ out)
{
    const int bid = blockIdx.x;
    const int chunk = bid % NCHUNK;
    const int ba = bid / NCHUNK;
    const int b = ba >> 2;   // / A
    const int a = ba & 3;    // % A
    const int l = chunk * 256 + (int)threadIdx.x;
    if (l >= L) return;

    // interp coords: t = clip((l - 1.5)/4, 0, R-1)
    float t = ((float)l - 1.5f) * 0.25f;
    t = fminf(fmaxf(t, 0.0f), (float)(R - 1));
    const int i0 = (int)t;                 // floor, t >= 0
    const int i1 = min(i0 + 1, R - 1);
    const float frac = t - (float)i0;

    float hire[S], hiim[S], pmre[S], pmim[S];
    float rre = 0.f, rim = 0.f;

    #pragma unroll
    for (int s = 0; s < S; ++s) {
        const int sb = s * B + b;
        int mp = m_arr[sb] % L; if (mp < 0) mp += L;
        const int j = (mp * l) % L;
        float sv, cv;
        __sincosf((TWO_PI / (float)L) * (float)j, &sv, &cv);
        const float2 h0 = havg[((size_t)sb * A + a) * R + i0];
        const float2 h1 = havg[((size_t)sb * A + a) * R + i1];
        const float hr = h0.x * (1.f - frac) + h1.x * frac;
        const float hi = h0.y * (1.f - frac) + h1.y * frac;
        hire[s] = hr; hiim[s] = hi; pmre[s] = cv; pmim[s] = sv;
        // recon += h_int * conj(ph_m)
        rre += hr * cv + hi * sv;
        rim += hi * cv - hr * sv;
    }

    const size_t off0 = ((size_t)(b * A + a)) * L + l;  // stream 0 LS
    const float resre = lsr[off0] - rre;
    const float resim = lsi[off0] - rim;

    #pragma unroll
    for (int s = 0; s < S; ++s) {
        // h_wr = h_interp + residual * ph_m
        const float wre = hire[s] + resre * pmre[s] - resim * pmim[s];
        const float wim = hiim[s] + resre * pmim[s] + resim * pmre[s];
        // final = h_wr * conj(ph_T)
        int jt = (toff_arr[s * B + b] * l) % L; if (jt < 0) jt += L;
        float sv, cv;
        __sincosf((TWO_PI / (float)L) * (float)jt, &sv, &cv);
        const float fre = wre * cv + wim * sv;
        const float fim = wim * cv - wre * sv;
        const size_t o = (((size_t)(s * B + b)) * A + a) * L + l;
        __builtin_nontemporal_store(fre, &out[o]);
        __builtin_nontemporal_store(fim, &out[(size_t)S * B * A * L + o]);
    }
}

}  // namespace

extern "C" void kernel_launch(void* const* d_in, const int* in_sizes, int n_in,
                              void* d_out, int out_size, void* d_ws, size_t ws_size,
                              hipStream_t stream) {
    (void)in_sizes; (void)n_in; (void)out_size; (void)ws_size;
    const float* lsr = (const float*)d_in[0];
    const float* lsi = (const float*)d_in[1];
    const int*   cs  = (const int*)d_in[2];
    // d_in[3] (noise_powers) is unused: mmse_module is identity.

    int* toff = (int*)d_ws;                              // 512 ints
    int* marr = toff + 512;                              // 512 ints
    float2* havg = (float2*)((char*)d_ws + 4096);        // S*B*A*R float2 = 13.4 MB

    k_stage1<<<S * B, 512, 0, stream>>>(lsr, lsi, cs, toff, marr, havg);
    k_final<<<B * A * NCHUNK, 256, 0, stream>>>(lsr, lsi, toff, marr, havg,
                                                (float*)d_out);
}